// Round 1
// 541.058 us; speedup vs baseline: 1.2081x; 1.2081x over previous
//
#include <hip/hip_runtime.h>
#include <hip/hip_bf16.h>

typedef __hip_bfloat16 bf16;
typedef __attribute__((ext_vector_type(8))) __bf16 bf16x8;
typedef __attribute__((ext_vector_type(4))) float  f32x4;

#define HW   65536
#define WID  256
#define CC   96
#define NB   4
static const size_t S_ELEMS = (size_t)NB * CC * HW;  // 25,165,824 elements

__device__ __forceinline__ float lo2f(unsigned u) { unsigned x = u << 16;        return __builtin_bit_cast(float, x); }
__device__ __forceinline__ float hi2f(unsigned u) { unsigned x = u & 0xffff0000u; return __builtin_bit_cast(float, x); }
__device__ __forceinline__ float b2f(bf16 v) { return __bfloat162float(v); }
__device__ __forceinline__ unsigned short f2bu(float f) {
    return __builtin_bit_cast(unsigned short, __float2bfloat16(f));
}

__device__ __forceinline__ void store8b(bf16* p, const float v[8]) {
    alignas(16) bf16 o[8];
#pragma unroll
    for (int i = 0; i < 8; ++i) o[i] = __float2bfloat16(v[i]);
    *reinterpret_cast<uint4*>(p) = *reinterpret_cast<const uint4*>(o);
}

// exact-GELU via Abramowitz-Stegun 7.1.26 erf (|err| < 1.5e-7)
__device__ __forceinline__ float gelu_erf(float v) {
    float z  = fabsf(v) * 0.70710678118654752f;
    float t  = __builtin_amdgcn_rcpf(1.f + 0.3275911f * z);
    float poly = t * (0.254829592f + t * (-0.284496736f + t * (1.421413741f
               + t * (-1.453152027f + t * 1.061405429f))));
    float erfz = 1.f - poly * __expf(-z * z);
    float erfv = copysignf(erfz, v);
    return 0.5f * v * (1.f + erfv);
}

// ---------------- Kernel 1: LayerNorm over channel dim of NCHW ----------------
__global__ __launch_bounds__(256) void ln_kernel(
    const float* __restrict__ x, const float* __restrict__ lw,
    const float* __restrict__ lb, bf16* __restrict__ y)
{
    int t  = blockIdx.x * 256 + threadIdx.x;   // [0, 131072)
    int b  = t >> 15;
    int hw = (t & 32767) * 2;
    size_t base = (size_t)b * CC * HW + hw;

    float s0 = 0.f, s1 = 0.f, q0 = 0.f, q1 = 0.f;
    for (int c = 0; c < CC; ++c) {
        float2 v = *reinterpret_cast<const float2*>(&x[base + (size_t)c * HW]);
        s0 += v.x; s1 += v.y; q0 += v.x * v.x; q1 += v.y * v.y;
    }
    float mu0 = s0 * (1.f / 96.f), mu1 = s1 * (1.f / 96.f);
    float rs0 = rsqrtf(q0 * (1.f / 96.f) - mu0 * mu0 + 1e-6f);
    float rs1 = rsqrtf(q1 * (1.f / 96.f) - mu1 * mu1 + 1e-6f);

    for (int c = 0; c < CC; ++c) {
        float2 v = *reinterpret_cast<const float2*>(&x[base + (size_t)c * HW]);
        float g = lw[c], be = lb[c];
        bf16 o[2];
        o[0] = __float2bfloat16((v.x - mu0) * rs0 * g + be);
        o[1] = __float2bfloat16((v.y - mu1) * rs1 * g + be);
        *reinterpret_cast<uint*>(&y[base + (size_t)c * HW]) = *reinterpret_cast<uint*>(o);
    }
}

// ---------------- conv1x1 via MFMA 16x16x32 bf16 ----------------
// GEMM: out[o][p] = sum_c W[o][c] * X[c][p].  A = W (M=COUT), B = X (N=positions).
// Block = 4 waves, tile M=COUT x N=128. Weights LDS [COUT][CIN+8] bf16 (A-frag =
// one aligned ds_read_b128). B-frags loaded straight global->VGPR (8 scalar loads,
// 16 consecutive positions/lane-group: coalesced, block covers full cachelines).
// Layouts (m89-verified): A[m=lane&15][k=quad*8+j]; B[k=quad*8+j][n=lane&15];
// D col=lane&15 (position), row=quad*4+reg (channel).
template <typename TI, typename TOT, int CIN, int COUT, bool GELU, bool HASRES>
__global__ __launch_bounds__(256) void conv1x1_mfma(
    const TI* __restrict__ in, const float* __restrict__ wgt,
    const float* __restrict__ bias, const float* __restrict__ resid,
    TOT* __restrict__ out)
{
    constexpr int CINP = CIN + 8;
    constexpr int MT   = COUT / 16;
    constexpr int KT   = CIN / 32;
    __shared__ unsigned short s_w[COUT * CINP];
    __shared__ float          s_b[COUT];

    const int tid  = threadIdx.x;
    const int lane = tid & 63;
    const int wave = tid >> 6;
    const int q    = lane >> 4;
    const int n    = lane & 15;

    const int pos0 = blockIdx.x * 128;
    const int b    = pos0 >> 16;
    const int hw0  = pos0 & 65535;

    // stage weights fp32 -> bf16 LDS, + bias
    constexpr int C4 = CIN / 4;
    for (int k = tid; k < COUT * C4; k += 256) {
        int o = k / C4, c4 = (k - o * C4) * 4;
        float4 w4 = *reinterpret_cast<const float4*>(&wgt[o * CIN + c4]);
        ushort4 pk = make_ushort4(f2bu(w4.x), f2bu(w4.y), f2bu(w4.z), f2bu(w4.w));
        *reinterpret_cast<ushort4*>(&s_w[o * CINP + c4]) = pk;
    }
    for (int k = tid; k < COUT; k += 256) s_b[k] = bias[k];
    __syncthreads();

    const TI* inb = in + (size_t)b * CIN * HW;
    const int p0  = hw0 + wave * 32 + n;
    const int p1  = p0 + 16;

    f32x4 acc[MT][2];
#pragma unroll
    for (int mt = 0; mt < MT; ++mt) {
        acc[mt][0] = {0.f, 0.f, 0.f, 0.f};
        acc[mt][1] = {0.f, 0.f, 0.f, 0.f};
    }

    for (int kt = 0; kt < KT; ++kt) {
        const int c0 = kt * 32 + q * 8;
        union { unsigned short u[8]; bf16x8 v; } bf0, bf1;
#pragma unroll
        for (int j = 0; j < 8; ++j) {
            const size_t rowo = (size_t)(c0 + j) * HW;
            if constexpr (__is_same(TI, float)) {
                bf0.u[j] = f2bu(inb[rowo + p0]);
                bf1.u[j] = f2bu(inb[rowo + p1]);
            } else {
                bf0.u[j] = *reinterpret_cast<const unsigned short*>(&inb[rowo + p0]);
                bf1.u[j] = *reinterpret_cast<const unsigned short*>(&inb[rowo + p1]);
            }
        }
#pragma unroll
        for (int mt = 0; mt < MT; ++mt) {
            union { unsigned short u[8]; bf16x8 v; } fa;
            *reinterpret_cast<uint4*>(fa.u) =
                *reinterpret_cast<const uint4*>(&s_w[(mt * 16 + n) * CINP + kt * 32 + q * 8]);
            acc[mt][0] = __builtin_amdgcn_mfma_f32_16x16x32_bf16(fa.v, bf0.v, acc[mt][0], 0, 0, 0);
            acc[mt][1] = __builtin_amdgcn_mfma_f32_16x16x32_bf16(fa.v, bf1.v, acc[mt][1], 0, 0, 0);
        }
    }

    const size_t obase = (size_t)b * COUT * HW;
#pragma unroll
    for (int mt = 0; mt < MT; ++mt) {
#pragma unroll
        for (int nt = 0; nt < 2; ++nt) {
            const int p = (nt == 0) ? p0 : p1;
#pragma unroll
            for (int r = 0; r < 4; ++r) {
                const int o = mt * 16 + q * 4 + r;
                float v = acc[mt][nt][r] + s_b[o];
                if constexpr (GELU) v = gelu_erf(v);
                const size_t idx = obase + (size_t)o * HW + p;
                if constexpr (HASRES) v += resid[idx];
                if constexpr (__is_same(TOT, float)) out[idx] = v;
                else                                 out[idx] = __float2bfloat16(v);
            }
        }
    }
}

// ---------------- Kernel 3: experts, LDS-staged stencil ----------------
// One block = one (b, c, h-tile of 8 rows). Stage the 20 needed xn rows and
// 10 needed t0 rows into LDS (zero-padded left/right cols and out-of-range
// rows), then compute all three depthwise experts from LDS windows.
// LDS row stride 272 elems (544 B, 16B-aligned); window read = 3x b128.
#define LW 272          // -8 .. 263 padded columns
#define XROWS 20        // h0-6 .. h0+13
#define TROWS 10        // h0-1 .. h0+8

__device__ __forceinline__ void load_win24_lds(const unsigned short* s, float win[24])
{
    uint4 c0 = *reinterpret_cast<const uint4*>(s);
    uint4 c1 = *reinterpret_cast<const uint4*>(s + 8);
    uint4 c2 = *reinterpret_cast<const uint4*>(s + 16);
    win[0]=lo2f(c0.x); win[1]=hi2f(c0.x); win[2]=lo2f(c0.y); win[3]=hi2f(c0.y);
    win[4]=lo2f(c0.z); win[5]=hi2f(c0.z); win[6]=lo2f(c0.w); win[7]=hi2f(c0.w);
    win[8]=lo2f(c1.x); win[9]=hi2f(c1.x); win[10]=lo2f(c1.y); win[11]=hi2f(c1.y);
    win[12]=lo2f(c1.z); win[13]=hi2f(c1.z); win[14]=lo2f(c1.w); win[15]=hi2f(c1.w);
    win[16]=lo2f(c2.x); win[17]=hi2f(c2.x); win[18]=lo2f(c2.y); win[19]=hi2f(c2.y);
    win[20]=lo2f(c2.z); win[21]=hi2f(c2.z); win[22]=lo2f(c2.w); win[23]=hi2f(c2.w);
}
__device__ __forceinline__ void apply3(const float wk[3], int dil,
                                       const float win[24], float acc[8])
{
#pragma unroll
    for (int kw = 0; kw < 3; ++kw) {
        float wv = wk[kw];
        int d = (kw - 1) * dil;
#pragma unroll
        for (int o = 0; o < 8; ++o) acc[o] += wv * win[o + 8 + d];
    }
}
__device__ __forceinline__ void apply5(const float wk[5],
                                       const float win[24], float acc[8])
{
#pragma unroll
    for (int kw = 0; kw < 5; ++kw) {
        float wv = wk[kw];
        int d = (kw - 2) * 3;
#pragma unroll
        for (int o = 0; o < 8; ++o) acc[o] += wv * win[o + 8 + d];
    }
}

__global__ __launch_bounds__(256) void experts_kernel(
    const bf16* __restrict__ xn, const bf16* __restrict__ t0,
    const float* __restrict__ w0, const float* __restrict__ b0,
    const float* __restrict__ w1, const float* __restrict__ b1,
    const float* __restrict__ w2, const float* __restrict__ b2,
    const float* __restrict__ sw, const float* __restrict__ prompt,
    bf16* __restrict__ xa)
{
    __shared__ unsigned short sx[XROWS * LW];
    __shared__ unsigned short st[TROWS * LW];

    const int tid = threadIdx.x;
    const int bid = blockIdx.x;
    const int h0  = (bid & 31) * 8;
    const int bc  = bid >> 5;
    const int b   = bc / 96;
    const int c   = bc - b * 96;
    const size_t pbase = (size_t)bc * HW;

    const bf16* xp = xn + pbase;
    const bf16* tp = t0 + pbase;

    // ---- stage: 34 uint4-chunks per padded row (chunk 0 and 33 are zero pads)
    const uint4 z4 = make_uint4(0u, 0u, 0u, 0u);
    for (int idx = tid; idx < XROWS * 34; idx += 256) {
        int row = idx / 34, ch = idx - row * 34;
        int gh  = h0 - 6 + row;
        uint4 v = z4;
        if (ch >= 1 && ch <= 32 && (unsigned)gh < 256u)
            v = *reinterpret_cast<const uint4*>(xp + gh * WID + (ch - 1) * 8);
        *reinterpret_cast<uint4*>(&sx[row * LW + ch * 8]) = v;
    }
    for (int idx = tid; idx < TROWS * 34; idx += 256) {
        int row = idx / 34, ch = idx - row * 34;
        int gh  = h0 - 1 + row;
        uint4 v = z4;
        if (ch >= 1 && ch <= 32 && (unsigned)gh < 256u)
            v = *reinterpret_cast<const uint4*>(tp + gh * WID + (ch - 1) * 8);
        *reinterpret_cast<uint4*>(&st[row * LW + ch * 8]) = v;
    }

    // ---- per-channel weights (block-uniform -> scalar loads)
    float wk0[9], wk1[9], wk2[25];
#pragma unroll
    for (int i = 0; i < 9; ++i)  wk0[i] = w0[c * 9 + i];
#pragma unroll
    for (int i = 0; i < 9; ++i)  wk1[i] = w1[c * 9 + i];
#pragma unroll
    for (int i = 0; i < 25; ++i) wk2[i] = w2[c * 25 + i];

    __syncthreads();

    const int wg  = tid & 31;
    const int r   = tid >> 5;          // output row within tile, [0,8)
    const int h   = h0 + r;
    const int w0p = wg * 8;            // output col start; window = cols [w0p-8, w0p+16)

    float acc0[8], acc1[8], acc2[8];
    {
        float bb0 = b0[c], bb1 = b1[c], bb2 = b2[c];
#pragma unroll
        for (int o = 0; o < 8; ++o) { acc0[o] = bb0; acc1[o] = bb1; acc2[o] = bb2; }
    }

    float win[24];
    // xn-row index in LDS for global row hh is (hh - h0 + 6) = r + (off+6)
    load_win24_lds(&sx[(r + 0)  * LW + w0p], win); apply5(&wk2[0],  win, acc2);  // h-6
    load_win24_lds(&sx[(r + 3)  * LW + w0p], win); apply5(&wk2[5],  win, acc2);  // h-3
    load_win24_lds(&sx[(r + 4)  * LW + w0p], win); apply3(&wk1[0], 2, win, acc1); // h-2
    load_win24_lds(&sx[(r + 6)  * LW + w0p], win);                                // h
    apply3(&wk1[3], 2, win, acc1); apply5(&wk2[10], win, acc2);
    load_win24_lds(&sx[(r + 8)  * LW + w0p], win); apply3(&wk1[6], 2, win, acc1); // h+2
    load_win24_lds(&sx[(r + 9)  * LW + w0p], win); apply5(&wk2[15], win, acc2);  // h+3
    load_win24_lds(&sx[(r + 12) * LW + w0p], win); apply5(&wk2[20], win, acc2);  // h+6
    // t0-row index in LDS for global row hh is (hh - h0 + 1) = r + (off+1)
    load_win24_lds(&st[(r + 0) * LW + w0p], win); apply3(&wk0[0], 1, win, acc0);  // h-1
    load_win24_lds(&st[(r + 1) * LW + w0p], win); apply3(&wk0[3], 1, win, acc0);  // h
    load_win24_lds(&st[(r + 2) * LW + w0p], win); apply3(&wk0[6], 1, win, acc0);  // h+1

    float s0 = sw[b * 3 + 0], s1 = sw[b * 3 + 1], s2 = sw[b * 3 + 2];
    float pr = 1.f + prompt[b * 96 + c];
    float ov[8];
#pragma unroll
    for (int o = 0; o < 8; ++o)
        ov[o] = (s0 * acc0[o] + s1 * acc1[o] + s2 * acc2[o]) * pr;
    store8b(&xa[pbase + h * WID + w0p], ov);
}

// ---------------- launch ----------------
extern "C" void kernel_launch(void* const* d_in, const int* in_sizes, int n_in,
                              void* d_out, int out_size, void* d_ws, size_t ws_size,
                              hipStream_t stream)
{
    const float* x       = (const float*)d_in[0];
    const float* prompt  = (const float*)d_in[1];
    const float* sw      = (const float*)d_in[2];
    const float* ln_w    = (const float*)d_in[3];
    const float* ln_b    = (const float*)d_in[4];
    const float* e0_pw_w = (const float*)d_in[5];
    const float* e0_pw_b = (const float*)d_in[6];
    const float* e0_dw_w = (const float*)d_in[7];
    const float* e0_dw_b = (const float*)d_in[8];
    const float* e1_dw_w = (const float*)d_in[9];
    const float* e1_dw_b = (const float*)d_in[10];
    const float* e2_dw_w = (const float*)d_in[11];
    const float* e2_dw_b = (const float*)d_in[12];
    const float* proj_w  = (const float*)d_in[13];
    const float* proj_b  = (const float*)d_in[14];
    const float* ffn1_w  = (const float*)d_in[15];
    const float* ffn1_b  = (const float*)d_in[16];
    const float* ffn2_w  = (const float*)d_in[17];
    const float* ffn2_b  = (const float*)d_in[18];

    float* out = (float*)d_out;                 // x1 lives here fp32 between k4..k6
    bf16*  ws  = (bf16*)d_ws;
    bf16*  A   = ws;                 // xn  bf16 (48 MB)
    bf16*  Bt  = ws + S_ELEMS;       // t0  bf16 (48 MB)
    bf16*  Cx  = ws + 2 * S_ELEMS;   // xa  bf16 (48 MB)  -> peak ws = 144 MB
    bf16*  E   = ws;                 // h (192 ch) bf16 (96 MB), reuses A+Bt once dead

    // 1) xn = LayerNorm_c(x)
    ln_kernel<<<512, 256, 0, stream>>>(x, ln_w, ln_b, A);
    // 2) t0 = conv1x1(xn, e0_pw)
    conv1x1_mfma<bf16, bf16, 96, 96, false, false>
        <<<2048, 256, 0, stream>>>(A, e0_pw_w, e0_pw_b, nullptr, Bt);
    // 3) xa = (s0*dw3(t0) + s1*dw3d2(xn) + s2*dw5d3(xn)) * (1+prompt)
    experts_kernel<<<12288, 256, 0, stream>>>(A, Bt, e0_dw_w, e0_dw_b, e1_dw_w, e1_dw_b,
                                              e2_dw_w, e2_dw_b, sw, prompt, Cx);
    // 4) x1 = x + conv1x1(xa, proj)  -> d_out (fp32)
    conv1x1_mfma<bf16, float, 96, 96, false, true>
        <<<2048, 256, 0, stream>>>(Cx, proj_w, proj_b, x, out);
    // 5) h = gelu(conv1x1(x1, ffn1)) -> E (bf16)
    conv1x1_mfma<float, bf16, 96, 192, true, false>
        <<<2048, 256, 0, stream>>>(out, ffn1_w, ffn1_b, nullptr, E);
    // 6) out = x1 + conv1x1(h, ffn2) -> d_out (in-place, per-thread same-address RMW)
    conv1x1_mfma<bf16, float, 192, 96, false, true>
        <<<2048, 256, 0, stream>>>(E, ffn2_w, ffn2_b, out, out);
}

// Round 2
// 516.969 us; speedup vs baseline: 1.2644x; 1.0466x over previous
//
#include <hip/hip_runtime.h>
#include <hip/hip_bf16.h>

typedef __hip_bfloat16 bf16;
typedef __attribute__((ext_vector_type(8))) __bf16 bf16x8;
typedef __attribute__((ext_vector_type(4))) float  f32x4;

#define HW   65536
#define WID  256
#define CC   96
#define NB   4
static const size_t S_ELEMS = (size_t)NB * CC * HW;  // 25,165,824 elements

__device__ __forceinline__ float lo2f(unsigned u) { unsigned x = u << 16;        return __builtin_bit_cast(float, x); }
__device__ __forceinline__ float hi2f(unsigned u) { unsigned x = u & 0xffff0000u; return __builtin_bit_cast(float, x); }
__device__ __forceinline__ unsigned short f2bu(float f) {
    return __builtin_bit_cast(unsigned short, __float2bfloat16(f));
}

__device__ __forceinline__ void store8b(bf16* p, const float v[8]) {
    alignas(16) bf16 o[8];
#pragma unroll
    for (int i = 0; i < 8; ++i) o[i] = __float2bfloat16(v[i]);
    *reinterpret_cast<uint4*>(p) = *reinterpret_cast<const uint4*>(o);
}

// exact-GELU via Abramowitz-Stegun 7.1.26 erf (|err| < 1.5e-7)
__device__ __forceinline__ float gelu_erf(float v) {
    float z  = fabsf(v) * 0.70710678118654752f;
    float t  = __builtin_amdgcn_rcpf(1.f + 0.3275911f * z);
    float poly = t * (0.254829592f + t * (-0.284496736f + t * (1.421413741f
               + t * (-1.453152027f + t * 1.061405429f))));
    float erfz = 1.f - poly * __expf(-z * z);
    float erfv = copysignf(erfz, v);
    return 0.5f * v * (1.f + erfv);
}

// ---------------- Kernel 1: LayerNorm over channel dim of NCHW ----------------
__global__ __launch_bounds__(256) void ln_kernel(
    const float* __restrict__ x, const float* __restrict__ lw,
    const float* __restrict__ lb, bf16* __restrict__ y)
{
    int t  = blockIdx.x * 256 + threadIdx.x;   // [0, 131072)
    int b  = t >> 15;
    int hw = (t & 32767) * 2;
    size_t base = (size_t)b * CC * HW + hw;

    float s0 = 0.f, s1 = 0.f, q0 = 0.f, q1 = 0.f;
    for (int c = 0; c < CC; ++c) {
        float2 v = *reinterpret_cast<const float2*>(&x[base + (size_t)c * HW]);
        s0 += v.x; s1 += v.y; q0 += v.x * v.x; q1 += v.y * v.y;
    }
    float mu0 = s0 * (1.f / 96.f), mu1 = s1 * (1.f / 96.f);
    float rs0 = rsqrtf(q0 * (1.f / 96.f) - mu0 * mu0 + 1e-6f);
    float rs1 = rsqrtf(q1 * (1.f / 96.f) - mu1 * mu1 + 1e-6f);

    for (int c = 0; c < CC; ++c) {
        float2 v = *reinterpret_cast<const float2*>(&x[base + (size_t)c * HW]);
        float g = lw[c], be = lb[c];
        bf16 o[2];
        o[0] = __float2bfloat16((v.x - mu0) * rs0 * g + be);
        o[1] = __float2bfloat16((v.y - mu1) * rs1 * g + be);
        *reinterpret_cast<uint*>(&y[base + (size_t)c * HW]) = *reinterpret_cast<uint*>(o);
    }
}

// ---------------- conv1x1 via MFMA 16x16x32 bf16, LDS-staged activations ------
// GEMM: out[o][p] = sum_c W[o][c] * X[c][p].  A = W (M=COUT), B = X (N=positions).
// Block = 4 waves, tile M=COUT x N=128 positions.
//   s_w [COUT][CIN]  bf16, XOR-swizzled (no pad)
//   s_x [128][96]    bf16, XOR-swizzled, X-tile transposed to [pos][chan];
//                    CIN=192 staged as two 96-channel halves (KSPLIT=2).
// Swizzle: elem_off ^= ((row&7)^((row>>3)&7))<<3  (16B granules). Verified:
// b128 frag reads (16 consecutive rows, fixed col) and stage writes (rows
// stride-8, fixed col) both land exactly 2-way on 32 banks -> free (m136).
// Global stage loads: lane reads 8 consecutive positions of one channel
// (uint4 / 2x float4) -> 256B contiguous per 16 lanes, perfectly coalesced.
// Layouts (m89-verified): A[m=lane&15][k=quad*8+j]; B[k=quad*8+j][n=lane&15];
// D col=lane&15 (position), row=quad*4+reg (channel).
__device__ __forceinline__ int swzo(int row, int col, int width) {
    return (row * width + col) ^ ((((row & 7) ^ ((row >> 3) & 7)) << 3));
}

template <typename TI, typename TOT, int CIN, int COUT, bool GELU, bool HASRES>
__global__ __launch_bounds__(256) void conv1x1_mfma(
    const TI* __restrict__ in, const float* __restrict__ wgt,
    const float* __restrict__ bias, const float* __restrict__ resid,
    TOT* __restrict__ out)
{
    constexpr int MT     = COUT / 16;
    constexpr int KSPLIT = CIN / 96;         // 1 (CIN=96) or 2 (CIN=192)
    constexpr int CS     = 96;               // staged channels per split
    static_assert(CIN == KSPLIT * CS, "CIN must be 96 or 192");

    __shared__ unsigned short s_w[COUT * CIN];
    __shared__ unsigned short s_x[128 * CS];
    __shared__ float          s_b[COUT];

    const int tid  = threadIdx.x;
    const int lane = tid & 63;
    const int wave = tid >> 6;
    const int q    = lane >> 4;
    const int n    = lane & 15;

    const int pos0 = blockIdx.x * 128;
    const int b    = pos0 >> 16;
    const int hw0  = pos0 & 65535;

    // ---- stage weights fp32 -> bf16 LDS (swizzled), + bias
    constexpr int C4 = CIN / 4;
    for (int k = tid; k < COUT * C4; k += 256) {
        int o = k / C4, c4 = (k - o * C4) * 4;
        float4 w4 = *reinterpret_cast<const float4*>(&wgt[o * CIN + c4]);
        ushort4 pk = make_ushort4(f2bu(w4.x), f2bu(w4.y), f2bu(w4.z), f2bu(w4.w));
        *reinterpret_cast<ushort4*>(&s_w[swzo(o, c4, CIN)]) = pk;
    }
    for (int k = tid; k < COUT; k += 256) s_b[k] = bias[k];

    const TI* inb = in + (size_t)b * CIN * HW;

    f32x4 acc[MT][2];
#pragma unroll
    for (int mt = 0; mt < MT; ++mt) {
        acc[mt][0] = {0.f, 0.f, 0.f, 0.f};
        acc[mt][1] = {0.f, 0.f, 0.f, 0.f};
    }

    const int pl0 = wave * 32 + n;   // tile-local position for bf0
    const int pl1 = pl0 + 16;        // tile-local position for bf1

#pragma unroll
    for (int ks = 0; ks < KSPLIT; ++ks) {
        if (ks) __syncthreads();     // previous s_x fully consumed

        // ---- stage X tile: [pos][chan] transposed, swizzled
        for (int idx = tid; idx < CS * 16; idx += 256) {
            const int c    = idx >> 4;
            const int pblk = idx & 15;
            const int row0 = pblk * 8;
            const TI* gp = inb + (size_t)(ks * CS + c) * HW + hw0 + row0;
            alignas(16) unsigned short u[8];
            if constexpr (__is_same(TI, float)) {
                float4 a  = *reinterpret_cast<const float4*>(gp);
                float4 b2 = *reinterpret_cast<const float4*>(gp + 4);
                u[0] = f2bu(a.x);  u[1] = f2bu(a.y);  u[2] = f2bu(a.z);  u[3] = f2bu(a.w);
                u[4] = f2bu(b2.x); u[5] = f2bu(b2.y); u[6] = f2bu(b2.z); u[7] = f2bu(b2.w);
            } else {
                *reinterpret_cast<uint4*>(u) = *reinterpret_cast<const uint4*>(gp);
            }
#pragma unroll
            for (int i = 0; i < 8; ++i)
                s_x[swzo(row0 + i, c, CS)] = u[i];
        }
        __syncthreads();

        // ---- MFMA over this K-split
#pragma unroll
        for (int kt = 0; kt < CS / 32; ++kt) {
            const int col = kt * 32 + q * 8;
            union { unsigned short u[8]; bf16x8 v; } bf0, bf1;
            *reinterpret_cast<uint4*>(bf0.u) =
                *reinterpret_cast<const uint4*>(&s_x[swzo(pl0, col, CS)]);
            *reinterpret_cast<uint4*>(bf1.u) =
                *reinterpret_cast<const uint4*>(&s_x[swzo(pl1, col, CS)]);
#pragma unroll
            for (int mt = 0; mt < MT; ++mt) {
                union { unsigned short u[8]; bf16x8 v; } fa;
                *reinterpret_cast<uint4*>(fa.u) =
                    *reinterpret_cast<const uint4*>(&s_w[swzo(mt * 16 + n, ks * CS + col, CIN)]);
                acc[mt][0] = __builtin_amdgcn_mfma_f32_16x16x32_bf16(fa.v, bf0.v, acc[mt][0], 0, 0, 0);
                acc[mt][1] = __builtin_amdgcn_mfma_f32_16x16x32_bf16(fa.v, bf1.v, acc[mt][1], 0, 0, 0);
            }
        }
    }

    // ---- epilogue
    const int p0 = hw0 + pl0;
    const int p1 = hw0 + pl1;
    const size_t obase = (size_t)b * COUT * HW;
#pragma unroll
    for (int mt = 0; mt < MT; ++mt) {
#pragma unroll
        for (int nt = 0; nt < 2; ++nt) {
            const int p = (nt == 0) ? p0 : p1;
#pragma unroll
            for (int r = 0; r < 4; ++r) {
                const int o = mt * 16 + q * 4 + r;
                float v = acc[mt][nt][r] + s_b[o];
                if constexpr (GELU) v = gelu_erf(v);
                const size_t idx = obase + (size_t)o * HW + p;
                if constexpr (HASRES) v += resid[idx];
                if constexpr (__is_same(TOT, float)) out[idx] = v;
                else                                 out[idx] = __float2bfloat16(v);
            }
        }
    }
}

// ---------------- Kernel 3: experts, LDS-staged stencil ----------------
#define LW 272          // -8 .. 263 padded columns
#define XROWS 20        // h0-6 .. h0+13
#define TROWS 10        // h0-1 .. h0+8

__device__ __forceinline__ void load_win24_lds(const unsigned short* s, float win[24])
{
    uint4 c0 = *reinterpret_cast<const uint4*>(s);
    uint4 c1 = *reinterpret_cast<const uint4*>(s + 8);
    uint4 c2 = *reinterpret_cast<const uint4*>(s + 16);
    win[0]=lo2f(c0.x); win[1]=hi2f(c0.x); win[2]=lo2f(c0.y); win[3]=hi2f(c0.y);
    win[4]=lo2f(c0.z); win[5]=hi2f(c0.z); win[6]=lo2f(c0.w); win[7]=hi2f(c0.w);
    win[8]=lo2f(c1.x); win[9]=hi2f(c1.x); win[10]=lo2f(c1.y); win[11]=hi2f(c1.y);
    win[12]=lo2f(c1.z); win[13]=hi2f(c1.z); win[14]=lo2f(c1.w); win[15]=hi2f(c1.w);
    win[16]=lo2f(c2.x); win[17]=hi2f(c2.x); win[18]=lo2f(c2.y); win[19]=hi2f(c2.y);
    win[20]=lo2f(c2.z); win[21]=hi2f(c2.z); win[22]=lo2f(c2.w); win[23]=hi2f(c2.w);
}
__device__ __forceinline__ void apply3(const float wk[3], int dil,
                                       const float win[24], float acc[8])
{
#pragma unroll
    for (int kw = 0; kw < 3; ++kw) {
        float wv = wk[kw];
        int d = (kw - 1) * dil;
#pragma unroll
        for (int o = 0; o < 8; ++o) acc[o] += wv * win[o + 8 + d];
    }
}
__device__ __forceinline__ void apply5(const float wk[5],
                                       const float win[24], float acc[8])
{
#pragma unroll
    for (int kw = 0; kw < 5; ++kw) {
        float wv = wk[kw];
        int d = (kw - 2) * 3;
#pragma unroll
        for (int o = 0; o < 8; ++o) acc[o] += wv * win[o + 8 + d];
    }
}

__global__ __launch_bounds__(256) void experts_kernel(
    const bf16* __restrict__ xn, const bf16* __restrict__ t0,
    const float* __restrict__ w0, const float* __restrict__ b0,
    const float* __restrict__ w1, const float* __restrict__ b1,
    const float* __restrict__ w2, const float* __restrict__ b2,
    const float* __restrict__ sw, const float* __restrict__ prompt,
    bf16* __restrict__ xa)
{
    __shared__ unsigned short sx[XROWS * LW];
    __shared__ unsigned short st[TROWS * LW];

    const int tid = threadIdx.x;
    const int bid = blockIdx.x;
    const int h0  = (bid & 31) * 8;
    const int bc  = bid >> 5;
    const int b   = bc / 96;
    const int c   = bc - b * 96;
    const size_t pbase = (size_t)bc * HW;

    const bf16* xp = xn + pbase;
    const bf16* tp = t0 + pbase;

    // ---- stage: 34 uint4-chunks per padded row (chunk 0 and 33 are zero pads)
    const uint4 z4 = make_uint4(0u, 0u, 0u, 0u);
    for (int idx = tid; idx < XROWS * 34; idx += 256) {
        int row = idx / 34, ch = idx - row * 34;
        int gh  = h0 - 6 + row;
        uint4 v = z4;
        if (ch >= 1 && ch <= 32 && (unsigned)gh < 256u)
            v = *reinterpret_cast<const uint4*>(xp + gh * WID + (ch - 1) * 8);
        *reinterpret_cast<uint4*>(&sx[row * LW + ch * 8]) = v;
    }
    for (int idx = tid; idx < TROWS * 34; idx += 256) {
        int row = idx / 34, ch = idx - row * 34;
        int gh  = h0 - 1 + row;
        uint4 v = z4;
        if (ch >= 1 && ch <= 32 && (unsigned)gh < 256u)
            v = *reinterpret_cast<const uint4*>(tp + gh * WID + (ch - 1) * 8);
        *reinterpret_cast<uint4*>(&st[row * LW + ch * 8]) = v;
    }

    // ---- per-channel weights (block-uniform -> scalar loads)
    float wk0[9], wk1[9], wk2[25];
#pragma unroll
    for (int i = 0; i < 9; ++i)  wk0[i] = w0[c * 9 + i];
#pragma unroll
    for (int i = 0; i < 9; ++i)  wk1[i] = w1[c * 9 + i];
#pragma unroll
    for (int i = 0; i < 25; ++i) wk2[i] = w2[c * 25 + i];

    __syncthreads();

    const int wg  = tid & 31;
    const int r   = tid >> 5;          // output row within tile, [0,8)
    const int h   = h0 + r;
    const int w0p = wg * 8;            // output col start; window = cols [w0p-8, w0p+16)

    float acc0[8], acc1[8], acc2[8];
    {
        float bb0 = b0[c], bb1 = b1[c], bb2 = b2[c];
#pragma unroll
        for (int o = 0; o < 8; ++o) { acc0[o] = bb0; acc1[o] = bb1; acc2[o] = bb2; }
    }

    float win[24];
    // xn-row index in LDS for global row hh is (hh - h0 + 6) = r + (off+6)
    load_win24_lds(&sx[(r + 0)  * LW + w0p], win); apply5(&wk2[0],  win, acc2);  // h-6
    load_win24_lds(&sx[(r + 3)  * LW + w0p], win); apply5(&wk2[5],  win, acc2);  // h-3
    load_win24_lds(&sx[(r + 4)  * LW + w0p], win); apply3(&wk1[0], 2, win, acc1); // h-2
    load_win24_lds(&sx[(r + 6)  * LW + w0p], win);                                // h
    apply3(&wk1[3], 2, win, acc1); apply5(&wk2[10], win, acc2);
    load_win24_lds(&sx[(r + 8)  * LW + w0p], win); apply3(&wk1[6], 2, win, acc1); // h+2
    load_win24_lds(&sx[(r + 9)  * LW + w0p], win); apply5(&wk2[15], win, acc2);  // h+3
    load_win24_lds(&sx[(r + 12) * LW + w0p], win); apply5(&wk2[20], win, acc2);  // h+6
    // t0-row index in LDS for global row hh is (hh - h0 + 1) = r + (off+1)
    load_win24_lds(&st[(r + 0) * LW + w0p], win); apply3(&wk0[0], 1, win, acc0);  // h-1
    load_win24_lds(&st[(r + 1) * LW + w0p], win); apply3(&wk0[3], 1, win, acc0);  // h
    load_win24_lds(&st[(r + 2) * LW + w0p], win); apply3(&wk0[6], 1, win, acc0);  // h+1

    float s0 = sw[b * 3 + 0], s1 = sw[b * 3 + 1], s2 = sw[b * 3 + 2];
    float pr = 1.f + prompt[b * 96 + c];
    float ov[8];
#pragma unroll
    for (int o = 0; o < 8; ++o)
        ov[o] = (s0 * acc0[o] + s1 * acc1[o] + s2 * acc2[o]) * pr;
    store8b(&xa[pbase + h * WID + w0p], ov);
}

// ---------------- launch ----------------
extern "C" void kernel_launch(void* const* d_in, const int* in_sizes, int n_in,
                              void* d_out, int out_size, void* d_ws, size_t ws_size,
                              hipStream_t stream)
{
    const float* x       = (const float*)d_in[0];
    const float* prompt  = (const float*)d_in[1];
    const float* sw      = (const float*)d_in[2];
    const float* ln_w    = (const float*)d_in[3];
    const float* ln_b    = (const float*)d_in[4];
    const float* e0_pw_w = (const float*)d_in[5];
    const float* e0_pw_b = (const float*)d_in[6];
    const float* e0_dw_w = (const float*)d_in[7];
    const float* e0_dw_b = (const float*)d_in[8];
    const float* e1_dw_w = (const float*)d_in[9];
    const float* e1_dw_b = (const float*)d_in[10];
    const float* e2_dw_w = (const float*)d_in[11];
    const float* e2_dw_b = (const float*)d_in[12];
    const float* proj_w  = (const float*)d_in[13];
    const float* proj_b  = (const float*)d_in[14];
    const float* ffn1_w  = (const float*)d_in[15];
    const float* ffn1_b  = (const float*)d_in[16];
    const float* ffn2_w  = (const float*)d_in[17];
    const float* ffn2_b  = (const float*)d_in[18];

    float* out = (float*)d_out;                 // x1 lives here fp32 between k4..k6
    bf16*  ws  = (bf16*)d_ws;
    bf16*  A   = ws;                 // xn  bf16 (48 MB)
    bf16*  Bt  = ws + S_ELEMS;       // t0  bf16 (48 MB)
    bf16*  Cx  = ws + 2 * S_ELEMS;   // xa  bf16 (48 MB)  -> peak ws = 144 MB
    bf16*  E   = ws;                 // h (192 ch) bf16 (96 MB), reuses A+Bt once dead

    // 1) xn = LayerNorm_c(x)
    ln_kernel<<<512, 256, 0, stream>>>(x, ln_w, ln_b, A);
    // 2) t0 = conv1x1(xn, e0_pw)
    conv1x1_mfma<bf16, bf16, 96, 96, false, false>
        <<<2048, 256, 0, stream>>>(A, e0_pw_w, e0_pw_b, nullptr, Bt);
    // 3) xa = (s0*dw3(t0) + s1*dw3d2(xn) + s2*dw5d3(xn)) * (1+prompt)
    experts_kernel<<<12288, 256, 0, stream>>>(A, Bt, e0_dw_w, e0_dw_b, e1_dw_w, e1_dw_b,
                                              e2_dw_w, e2_dw_b, sw, prompt, Cx);
    // 4) x1 = x + conv1x1(xa, proj)  -> d_out (fp32)
    conv1x1_mfma<bf16, float, 96, 96, false, true>
        <<<2048, 256, 0, stream>>>(Cx, proj_w, proj_b, x, out);
    // 5) h = gelu(conv1x1(x1, ffn1)) -> E (bf16)
    conv1x1_mfma<float, bf16, 96, 192, true, false>
        <<<2048, 256, 0, stream>>>(out, ffn1_w, ffn1_b, nullptr, E);
    // 6) out = x1 + conv1x1(h, ffn2) -> d_out (in-place, per-thread same-address RMW)
    conv1x1_mfma<bf16, float, 192, 96, false, true>
        <<<2048, 256, 0, stream>>>(E, ffn2_w, ffn2_b, out, out);
}